// Round 3
// baseline (1487.057 us; speedup 1.0000x reference)
//
#include <hip/hip_runtime.h>
#include <math.h>

#define HH 128
#define HP 64   // u32 pairs per 128-feature row

typedef __attribute__((ext_vector_type(8))) short short8;
typedef __attribute__((ext_vector_type(4))) float float4v;
typedef __attribute__((ext_vector_type(4))) unsigned uint4v;

// ---------- helpers ----------
__device__ __forceinline__ float blo(unsigned w){ return __uint_as_float(w << 16); }
__device__ __forceinline__ float bhi(unsigned w){ return __uint_as_float(w & 0xffff0000u); }
__device__ __forceinline__ unsigned short f2b(float x){
  unsigned u = __float_as_uint(x);
  u += 0x7fffu + ((u >> 16) & 1u);           // RNE to bf16
  return (unsigned short)(u >> 16);
}
__device__ __forceinline__ unsigned pack2(float a, float b){
  return (unsigned)f2b(a) | ((unsigned)f2b(b) << 16);
}
__device__ __forceinline__ float silu_f(float x){ return x / (1.f + __expf(-x)); }

// ---------- 0) counting sort of edges by dst ----------
__global__ void hist_kernel(const int* __restrict__ dst, int* __restrict__ bins, int E)
{
  int i = blockIdx.x * blockDim.x + threadIdx.x;
  int stride = gridDim.x * blockDim.x;
  for (; i < E; i += stride) atomicAdd(&bins[dst[i]], 1);
}

__global__ __launch_bounds__(1024) void scan_kernel(
    const int* __restrict__ bins, int* __restrict__ cursor, int N)
{
  __shared__ int sums[1024];
  const int t = threadIdx.x;
  const int chunk = (N + 1023) >> 10;
  const int lo = t * chunk;
  const int hi = min(lo + chunk, N);
  int s = 0;
  for (int i = lo; i < hi; ++i) s += bins[i];
  sums[t] = s;
  __syncthreads();
  for (int off = 1; off < 1024; off <<= 1) {
    int v = (t >= off) ? sums[t - off] : 0;
    __syncthreads();
    sums[t] += v;
    __syncthreads();
  }
  int run = (t > 0) ? sums[t - 1] : 0;       // exclusive base for this chunk
  for (int i = lo; i < hi; ++i) { cursor[i] = run; run += bins[i]; }
}

__global__ void scatter_kernel(const int* __restrict__ dst, int* __restrict__ cursor,
                               int* __restrict__ perm, int E)
{
  int i = blockIdx.x * blockDim.x + threadIdx.x;
  int stride = gridDim.x * blockDim.x;
  for (; i < E; i += stride) {
    int p = atomicAdd(&cursor[dst[i]], 1);
    perm[p] = i;
  }
}

// ---------- 1) per-node precompute: A = h@W[0:128] + bias, B = h@W[128:256] ----------
__global__ __launch_bounds__(256) void precompute_kernel(
    const float* __restrict__ h, const float* __restrict__ W,
    const float* __restrict__ bias,
    unsigned* __restrict__ Aout, unsigned* __restrict__ Bout, int N)
{
  __shared__ unsigned Wl[256 * HP];           // 64 KB, rows 0..255 packed bf16
  int t = threadIdx.x;
  const float2* W2 = (const float2*)W;
  for (int i = t; i < 256 * HP; i += 256) {
    float2 w = W2[i];
    Wl[i] = pack2(w.x, w.y);
  }
  __syncthreads();

  int wid = blockIdx.x * 4 + (t >> 6);
  int nw  = gridDim.x * 4;
  int jp  = t & 63;
  for (int n = wid; n < N; n += nw) {
    const float4* hn = (const float4*)(h + (size_t)n * HH);
    float a0 = 0.f, a1 = 0.f, b0 = 0.f, b1 = 0.f;
    #pragma unroll 8
    for (int k4 = 0; k4 < 32; ++k4) {
      float4 hv = hn[k4];                     // wave-uniform broadcast load
      float xs[4] = {hv.x, hv.y, hv.z, hv.w};
      #pragma unroll
      for (int u = 0; u < 4; ++u) {
        int k = 4 * k4 + u;
        unsigned wa = Wl[k * HP + jp];
        unsigned wb = Wl[(128 + k) * HP + jp];
        a0 += xs[u] * blo(wa); a1 += xs[u] * bhi(wa);
        b0 += xs[u] * blo(wb); b1 += xs[u] * bhi(wb);
      }
    }
    a0 += bias[2 * jp]; a1 += bias[2 * jp + 1];
    Aout[(size_t)n * HP + jp] = pack2(a0, a1);
    Bout[(size_t)n * HP + jp] = pack2(b0, b1);
  }
}

// ---------- 2) MFMA edge kernels: MODE 0 = edge MLP (att -> h_agg), MODE 1 = coord MLP (-> x_agg) ----------
// v3 = v2 compute structure (tail MFMA, register W2 frags, dbuf staging)
//    + dst-sorted edge order via perm[] (B-gather locality, contiguous h_agg sweep)
//    + in-register atomic run-merging.
template<int MODE>
__global__ __launch_bounds__(256, 4) void edge_kernel(
    const unsigned* __restrict__ Apart, const unsigned* __restrict__ Bpart,
    const float* __restrict__ W1,       // (276,128); rows 256..275 = tail
    const float* __restrict__ W2, const float* __restrict__ b2,
    const float* __restrict__ Wv,       // Wa (mode0) or Wc3 (mode1), [128]
    const float* __restrict__ ba_p,     // ba (mode0), unused mode1
    const int* __restrict__ src, const int* __restrict__ dst,
    const int* __restrict__ perm,
    const float* __restrict__ coords, const float* __restrict__ afeat,
    float* __restrict__ out_agg, int E)
{
  // mhl: stride 68 u32 -> b128 frag reads 2-way (free)
  __shared__ unsigned mhl[32 * 68];                 // 8.5 KB bf16-pairs
  __shared__ float    T[32 * 132];                  // 16.9 KB tail-MFMA out
  __shared__ unsigned short tailsA[2][32 * 40];     // 5 KB: A-frag layout [edge][k], k>=20 zero
  __shared__ float    dif[2][32 * 4];               // dx,dy,dz,rad
  __shared__ int      sl[2][32], dl[2][32], el[2][32];
  __shared__ float    p_lds[4][16];

  const int t = threadIdx.x;
  const int lane = t & 63;
  const int w = t >> 6;
  const int mtile = w >> 1;                   // 0/1 (16-edge half)
  const int nhalf = w & 1;                    // 0/1 (64-col half)
  const int col = lane & 15;
  const int quad = lane >> 4;
  const int n0 = nhalf * 64 + col;            // + nt*16

  // zero tailsA fully once (k=20..39 pad must stay 0; stage only writes k<20)
  for (int i = t; i < 2 * 32 * 20; i += 256) ((unsigned*)tailsA)[i] = 0u;

  // ---- persistent register fragments ----
  uint4v w2f[4][4];                           // layer-2 B-frags [nt][ks]
  #pragma unroll
  for (int nt = 0; nt < 4; ++nt) {
    const int n = n0 + nt * 16;
    #pragma unroll
    for (int ks = 0; ks < 4; ++ks) {
      const int kb = ks * 32 + quad * 8;
      unsigned u0 = pack2(W2[(size_t)(kb+0)*128+n], W2[(size_t)(kb+1)*128+n]);
      unsigned u1 = pack2(W2[(size_t)(kb+2)*128+n], W2[(size_t)(kb+3)*128+n]);
      unsigned u2 = pack2(W2[(size_t)(kb+4)*128+n], W2[(size_t)(kb+5)*128+n]);
      unsigned u3 = pack2(W2[(size_t)(kb+6)*128+n], W2[(size_t)(kb+7)*128+n]);
      w2f[nt][ks] = (uint4v){u0, u1, u2, u3};
    }
  }
  uint4v wtf[4];                              // tail B-frags (W1 rows 256..275, K=32 zero-pad)
  #pragma unroll
  for (int nt = 0; nt < 4; ++nt) {
    const int n = n0 + nt * 16;
    unsigned u[4];
    #pragma unroll
    for (int i = 0; i < 4; ++i) {
      const int k0 = quad * 8 + 2 * i;
      float a = (k0     < 20) ? W1[(size_t)(256 + k0    ) * 128 + n] : 0.f;
      float b = (k0 + 1 < 20) ? W1[(size_t)(256 + k0 + 1) * 128 + n] : 0.f;
      u[i] = pack2(a, b);
    }
    wtf[nt] = (uint4v){u[0], u[1], u[2], u[3]};
  }
  float b2reg[4], wvreg[4];
  #pragma unroll
  for (int nt = 0; nt < 4; ++nt) {
    b2reg[nt] = b2[n0 + nt * 16];
    wvreg[nt] = Wv[n0 + nt * 16];
  }
  const float bav = (MODE == 0) ? ba_p[0] : 0.f;

  __syncthreads();                            // pad zeros visible before first stage

  // ---- stage per-edge scalars + tail A-fragment for tile into buffer b ----
  auto stage = [&](int tl, int b) {
    const int e0s = tl * 32;
    if (t < 32) {
      int ep = e0s + t;
      int eg = (ep < E) ? perm[ep] : -1;
      el[b][t] = eg;
      int s = 0, d = 0;
      if (eg >= 0) { s = src[eg]; d = dst[eg]; }
      sl[b][t] = s; dl[b][t] = d;
      float dx = coords[s*3+0] - coords[d*3+0];
      float dy = coords[s*3+1] - coords[d*3+1];
      float dz = coords[s*3+2] - coords[d*3+2];
      float rad = sqrtf(dx*dx + dy*dy + dz*dz);
      dif[b][t*4+0] = dx; dif[b][t*4+1] = dy;
      dif[b][t*4+2] = dz; dif[b][t*4+3] = rad;
      unsigned* ta = (unsigned*)&tailsA[b][t * 40];
      ta[0] = pack2(rad, fabsf(dx));
      ta[1] = pack2(fabsf(dy), fabsf(dz));
    }
    #pragma unroll
    for (int i = t; i < 512; i += 256) {
      int e = i >> 4, f = i & 15;
      int ep = e0s + e;
      int eg = (ep < E) ? perm[ep] : -1;
      tailsA[b][e * 40 + 4 + f] =
          (eg >= 0) ? f2b(afeat[(size_t)eg * 16 + f]) : (unsigned short)0;
    }
  };

  const int ntiles = (E + 31) >> 5;
  int tile = blockIdx.x;
  if (tile < ntiles) stage(tile, 0);
  int buf = 0;

  for (; tile < ntiles; tile += gridDim.x, buf ^= 1) {
    __syncthreads();                          // stage[buf] visible; prev-tile LDS reads done
    const int eb = w * 8;

    // ---- issue long-latency gathers now; consume after next barrier ----
    unsigned wa[8], wb[8];
    #pragma unroll
    for (int i = 0; i < 8; ++i) {
      wa[i] = Apart[(size_t)sl[buf][eb + i] * HP + lane];
      wb[i] = Bpart[(size_t)dl[buf][eb + i] * HP + lane];   // sorted: ~2 distinct rows
    }

    // ---- tail MFMA: T[edge][n] = tails(20d) @ W1tail ----
    {
      const unsigned short* ap = &tailsA[buf][(mtile * 16 + col) * 40 + quad * 8];
      short8 af = __builtin_bit_cast(short8, *(const uint4v*)ap);
      float4v acct[4] = {{0,0,0,0},{0,0,0,0},{0,0,0,0},{0,0,0,0}};
      #pragma unroll
      for (int nt = 0; nt < 4; ++nt)
        acct[nt] = __builtin_amdgcn_mfma_f32_16x16x32_bf16(
            af, __builtin_bit_cast(short8, wtf[nt]), acct[nt], 0, 0, 0);
      #pragma unroll
      for (int nt = 0; nt < 4; ++nt)
        #pragma unroll
        for (int r = 0; r < 4; ++r)
          T[(mtile * 16 + quad * 4 + r) * 132 + n0 + nt * 16] = acct[nt][r];
    }
    __syncthreads();                          // T ready

    // ---- phase A: combine gathered A/B parts + tail, silu, pack to mhl ----
    #pragma unroll
    for (int i = 0; i < 8; ++i) {
      const int e = eb + i;
      float2 tv = *(const float2*)&T[e * 132 + 2 * lane];
      float t0 = blo(wa[i]) + blo(wb[i]) + tv.x;
      float t1 = bhi(wa[i]) + bhi(wb[i]) + tv.y;
      mhl[e * 68 + lane] = pack2(silu_f(t0), silu_f(t1));
    }
    __syncthreads();                          // mhl ready

    // ---- phase B: layer 2 via MFMA (B-frags in registers) ----
    float4v acc[4] = {{0,0,0,0},{0,0,0,0},{0,0,0,0},{0,0,0,0}};
    {
      const unsigned* abase = &mhl[(mtile * 16 + col) * 68 + quad * 4];
      #pragma unroll
      for (int ks = 0; ks < 4; ++ks) {
        short8 af = __builtin_bit_cast(short8, *(const uint4v*)(abase + ks * 16));
        #pragma unroll
        for (int nt = 0; nt < 4; ++nt)
          acc[nt] = __builtin_amdgcn_mfma_f32_16x16x32_bf16(
              af, __builtin_bit_cast(short8, w2f[nt][ks]), acc[nt], 0, 0, 0);
      }
    }

    // ---- epilogue: bias + silu (in place) + head dot, cross-wave reduce ----
    float p[4] = {0.f, 0.f, 0.f, 0.f};
    #pragma unroll
    for (int nt = 0; nt < 4; ++nt)
      #pragma unroll
      for (int r = 0; r < 4; ++r) {
        float v = silu_f(acc[nt][r] + b2reg[nt]);
        acc[nt][r] = v;                       // reuse acc as vv
        p[r] += v * wvreg[nt];
      }
    #pragma unroll
    for (int r = 0; r < 4; ++r) {
      #pragma unroll
      for (int off = 1; off < 16; off <<= 1) p[r] += __shfl_xor(p[r], off, 64);
    }
    if (col == 0) {
      #pragma unroll
      for (int r = 0; r < 4; ++r) p_lds[w][quad * 4 + r] = p[r];
    }
    __syncthreads();                          // p_lds ready

    // ---- scatter: dst-sorted -> run-merged atomics ----
    int key[4];
    float attr[4];
    #pragma unroll
    for (int r = 0; r < 4; ++r) {
      const int le = quad * 4 + r;
      const int ei = mtile * 16 + le;
      key[r] = (el[buf][ei] >= 0) ? dl[buf][ei] : -1;
      const float pfull = p_lds[w][le] + p_lds[w ^ 1][le];
      if (MODE == 0) attr[r] = 1.f / (1.f + __expf(-(pfull + bav)));
      else           attr[r] = pfull / (dif[buf][ei * 4 + 3] + 1.f);
    }

    if (MODE == 0) {
      #pragma unroll
      for (int nt = 0; nt < 4; ++nt) {
        const int n = n0 + nt * 16;
        float a2 = 0.f;
        #pragma unroll
        for (int r = 0; r < 4; ++r) {
          if (key[r] >= 0) a2 += attr[r] * acc[nt][r];
          if (r == 3 || key[r + 1] != key[r]) {
            if (key[r] >= 0)
              unsafeAtomicAdd(&out_agg[(size_t)key[r] * HH + n], a2);
            a2 = 0.f;
          }
        }
      }
    } else {
      if (nhalf == 0 && col < 3) {
        float a2 = 0.f;
        #pragma unroll
        for (int r = 0; r < 4; ++r) {
          const int ei = mtile * 16 + quad * 4 + r;
          if (key[r] >= 0) a2 += attr[r] * dif[buf][ei * 4 + col];
          if (r == 3 || key[r + 1] != key[r]) {
            if (key[r] >= 0)
              unsafeAtomicAdd(&out_agg[(size_t)key[r] * 3 + col], a2);
            a2 = 0.f;
          }
        }
      }
    }

    // ---- stage next tile into the other buffer (disjoint LDS; no barrier) ----
    if (tile + gridDim.x < ntiles) stage(tile + gridDim.x, buf ^ 1);
  }
}

// ---------- 3) node MLP layer 1: g = silu([h, h_agg] @ Wn1 + bn1), bf16-packed ----------
__global__ __launch_bounds__(256) void node_l1_kernel(
    const float* __restrict__ h, const float* __restrict__ h_agg,
    const float* __restrict__ Wn1, const float* __restrict__ bn1,
    unsigned* __restrict__ g, int N)
{
  __shared__ unsigned Wl[256 * HP];           // 64 KB
  int t = threadIdx.x;
  const float2* W2 = (const float2*)Wn1;
  for (int i = t; i < 256 * HP; i += 256) { float2 w = W2[i]; Wl[i] = pack2(w.x, w.y); }
  __syncthreads();

  int wid = blockIdx.x * 4 + (t >> 6);
  int nw  = gridDim.x * 4;
  int jp  = t & 63;
  for (int n = wid; n < N; n += nw) {
    float a0 = bn1[2*jp], a1 = bn1[2*jp + 1];
    const float4* hn = (const float4*)(h + (size_t)n * HH);
    const float4* gn = (const float4*)(h_agg + (size_t)n * HH);
    #pragma unroll 4
    for (int k4 = 0; k4 < 32; ++k4) {
      float4 hv = hn[k4];
      float xs[4] = {hv.x, hv.y, hv.z, hv.w};
      #pragma unroll
      for (int u = 0; u < 4; ++u) {
        unsigned w = Wl[(4*k4 + u) * HP + jp];
        a0 += xs[u] * blo(w); a1 += xs[u] * bhi(w);
      }
    }
    #pragma unroll 4
    for (int k4 = 0; k4 < 32; ++k4) {
      float4 hv = gn[k4];
      float xs[4] = {hv.x, hv.y, hv.z, hv.w};
      #pragma unroll
      for (int u = 0; u < 4; ++u) {
        unsigned w = Wl[(128 + 4*k4 + u) * HP + jp];
        a0 += xs[u] * blo(w); a1 += xs[u] * bhi(w);
      }
    }
    g[(size_t)n * HP + jp] = pack2(silu_f(a0), silu_f(a1));
  }
}

// ---------- 4) node MLP layer 2: h_out = h + g @ Wn2 + bn2 ----------
__global__ __launch_bounds__(256) void node_l2_kernel(
    const unsigned* __restrict__ g, const float* __restrict__ h,
    const float* __restrict__ Wn2, const float* __restrict__ bn2,
    float* __restrict__ hout, int N)
{
  __shared__ unsigned Wl[128 * HP];           // 32 KB
  int t = threadIdx.x;
  const float2* W2 = (const float2*)Wn2;
  for (int i = t; i < 128 * HP; i += 256) { float2 w = W2[i]; Wl[i] = pack2(w.x, w.y); }
  __syncthreads();

  int wid = blockIdx.x * 4 + (t >> 6);
  int nw  = gridDim.x * 4;
  int jp  = t & 63;
  for (int n = wid; n < N; n += nw) {
    float a0 = bn2[2*jp], a1 = bn2[2*jp + 1];
    const uint2* gn = (const uint2*)(g + (size_t)n * HP);
    #pragma unroll 4
    for (int k2 = 0; k2 < 32; ++k2) {
      uint2 gp = gn[k2];                      // 4 bf16 inputs
      float x0 = blo(gp.x), x1 = bhi(gp.x), x2 = blo(gp.y), x3 = bhi(gp.y);
      unsigned w0 = Wl[(4*k2    ) * HP + jp];
      unsigned w1 = Wl[(4*k2 + 1) * HP + jp];
      unsigned w2 = Wl[(4*k2 + 2) * HP + jp];
      unsigned w3 = Wl[(4*k2 + 3) * HP + jp];
      a0 += x0*blo(w0) + x1*blo(w1) + x2*blo(w2) + x3*blo(w3);
      a1 += x0*bhi(w0) + x1*bhi(w1) + x2*bhi(w2) + x3*bhi(w3);
    }
    float2 hv = ((const float2*)h)[(size_t)n * HP + jp];
    ((float2*)hout)[(size_t)n * HP + jp] = make_float2(hv.x + a0, hv.y + a1);
  }
}

// ---------- 5) coords_out = coords + x_agg ----------
__global__ void coords_out_kernel(const float* __restrict__ coords,
                                  const float* __restrict__ x_agg,
                                  float* __restrict__ out, int n3)
{
  int i = blockIdx.x * blockDim.x + threadIdx.x;
  if (i < n3) out[i] = coords[i] + x_agg[i];
}

extern "C" void kernel_launch(void* const* d_in, const int* in_sizes, int n_in,
                              void* d_out, int out_size, void* d_ws, size_t ws_size,
                              hipStream_t stream)
{
  const float* h      = (const float*)d_in[0];
  const float* coords = (const float*)d_in[1];
  const float* afeat  = (const float*)d_in[2];
  const int*   src    = (const int*)d_in[3];
  const int*   dst    = (const int*)d_in[4];
  const float* We1 = (const float*)d_in[5];
  const float* be1 = (const float*)d_in[6];
  const float* We2 = (const float*)d_in[7];
  const float* be2 = (const float*)d_in[8];
  const float* Wa  = (const float*)d_in[9];
  const float* ba  = (const float*)d_in[10];
  const float* Wn1 = (const float*)d_in[11];
  const float* bn1 = (const float*)d_in[12];
  const float* Wn2 = (const float*)d_in[13];
  const float* bn2 = (const float*)d_in[14];
  const float* Wc1 = (const float*)d_in[15];
  const float* bc1 = (const float*)d_in[16];
  const float* Wc2 = (const float*)d_in[17];
  const float* bc2 = (const float*)d_in[18];
  const float* Wc3 = (const float*)d_in[19];

  const int E = in_sizes[3];
  const int N = in_sizes[0] / HH;

  unsigned* A1 = (unsigned*)d_ws;
  unsigned* B1 = A1 + (size_t)N * HP;
  unsigned* Ac = B1 + (size_t)N * HP;
  unsigned* Bc = Ac + (size_t)N * HP;
  float* h_agg = (float*)(Bc + (size_t)N * HP);
  float* x_agg = h_agg + (size_t)N * HH;
  int*   bins   = (int*)(x_agg + (size_t)N * 3);
  int*   cursor = bins + N;
  int*   perm   = cursor + N;
  unsigned* gbuf = A1;                        // reuse after edge kernels finish

  // one memset covers h_agg + x_agg + bins (contiguous)
  hipMemsetAsync(h_agg, 0,
                 ((size_t)N * HH + (size_t)N * 3 + (size_t)N) * sizeof(float), stream);

  // ---- counting sort of edges by dst ----
  hist_kernel<<<512, 256, 0, stream>>>(dst, bins, E);
  scan_kernel<<<1, 1024, 0, stream>>>(bins, cursor, N);
  scatter_kernel<<<512, 256, 0, stream>>>(dst, cursor, perm, E);

  precompute_kernel<<<512, 256, 0, stream>>>(h, We1, be1, A1, B1, N);
  precompute_kernel<<<512, 256, 0, stream>>>(h, Wc1, bc1, Ac, Bc, N);

  edge_kernel<0><<<1024, 256, 0, stream>>>(A1, B1, We1, We2, be2, Wa, ba,
                                           src, dst, perm, coords, afeat, h_agg, E);
  edge_kernel<1><<<1024, 256, 0, stream>>>(Ac, Bc, Wc1, Wc2, bc2, Wc3, nullptr,
                                           src, dst, perm, coords, afeat, x_agg, E);

  node_l1_kernel<<<512, 256, 0, stream>>>(h, h_agg, Wn1, bn1, gbuf, N);
  node_l2_kernel<<<1024, 256, 0, stream>>>(gbuf, h, Wn2, bn2, (float*)d_out, N);
  coords_out_kernel<<<(N * 3 + 255) / 256, 256, 0, stream>>>(
      coords, x_agg, (float*)d_out + (size_t)N * HH, N * 3);
}

// Round 4
// 1120.571 us; speedup vs baseline: 1.3271x; 1.3271x over previous
//
#include <hip/hip_runtime.h>
#include <math.h>

#define HH 128
#define HP 64   // u32 pairs per 128-feature row

typedef __attribute__((ext_vector_type(8))) short short8;
typedef __attribute__((ext_vector_type(4))) float float4v;
typedef __attribute__((ext_vector_type(4))) unsigned uint4v;

// ---------- helpers ----------
__device__ __forceinline__ float blo(unsigned w){ return __uint_as_float(w << 16); }
__device__ __forceinline__ float bhi(unsigned w){ return __uint_as_float(w & 0xffff0000u); }
__device__ __forceinline__ unsigned short f2b(float x){
  unsigned u = __float_as_uint(x);
  u += 0x7fffu + ((u >> 16) & 1u);           // RNE to bf16
  return (unsigned short)(u >> 16);
}
__device__ __forceinline__ unsigned pack2(float a, float b){
  return (unsigned)f2b(a) | ((unsigned)f2b(b) << 16);
}
__device__ __forceinline__ float silu_f(float x){ return x / (1.f + __expf(-x)); }

// ---------- 1) per-node precompute: A = h@W[0:128] + bias, B = h@W[128:256] ----------
__global__ __launch_bounds__(256) void precompute_kernel(
    const float* __restrict__ h, const float* __restrict__ W,
    const float* __restrict__ bias,
    unsigned* __restrict__ Aout, unsigned* __restrict__ Bout, int N)
{
  __shared__ unsigned Wl[256 * HP];           // 64 KB, rows 0..255 packed bf16
  int t = threadIdx.x;
  const float2* W2 = (const float2*)W;
  for (int i = t; i < 256 * HP; i += 256) {
    float2 w = W2[i];
    Wl[i] = pack2(w.x, w.y);
  }
  __syncthreads();

  int wid = blockIdx.x * 4 + (t >> 6);
  int nw  = gridDim.x * 4;
  int jp  = t & 63;
  for (int n = wid; n < N; n += nw) {
    const float4* hn = (const float4*)(h + (size_t)n * HH);
    float a0 = 0.f, a1 = 0.f, b0 = 0.f, b1 = 0.f;
    #pragma unroll 8
    for (int k4 = 0; k4 < 32; ++k4) {
      float4 hv = hn[k4];                     // wave-uniform broadcast load
      float xs[4] = {hv.x, hv.y, hv.z, hv.w};
      #pragma unroll
      for (int u = 0; u < 4; ++u) {
        int k = 4 * k4 + u;
        unsigned wa = Wl[k * HP + jp];
        unsigned wb = Wl[(128 + k) * HP + jp];
        a0 += xs[u] * blo(wa); a1 += xs[u] * bhi(wa);
        b0 += xs[u] * blo(wb); b1 += xs[u] * bhi(wb);
      }
    }
    a0 += bias[2 * jp]; a1 += bias[2 * jp + 1];
    Aout[(size_t)n * HP + jp] = pack2(a0, a1);
    Bout[(size_t)n * HP + jp] = pack2(b0, b1);
  }
}

// ---------- 2) MFMA edge kernels: MODE 0 = edge MLP (att -> h_agg), MODE 1 = coord MLP (-> x_agg) ----------
// v4 = v0 memory structure (768 blocks, 3/CU, W2Ts in LDS, single-buffered stage,
//      unsorted, plain atomics)  +  tail-dot via MFMA whose C-layout matches
//      phase A's lane ownership (tail term never leaves registers).
template<int MODE>
__global__ __launch_bounds__(256, 3) void edge_kernel(
    const unsigned* __restrict__ Apart, const unsigned* __restrict__ Bpart,
    const float* __restrict__ W1,       // (276,128); rows 256..275 = tail
    const float* __restrict__ W2, const float* __restrict__ b2,
    const float* __restrict__ Wv,       // Wa (mode0) or Wc3 (mode1), [128]
    const float* __restrict__ ba_p,     // ba (mode0), unused mode1
    const int* __restrict__ src, const int* __restrict__ dst,
    const float* __restrict__ coords, const float* __restrict__ afeat,
    float* __restrict__ out_agg, int E)
{
  // strides 136 shorts (=272 B) keep b128 fragment reads 16B-aligned and 2-way-only
  __shared__ unsigned short W2Ts[128 * 136];  // 34 KB bf16, n-major: W2T[n][k]
  __shared__ unsigned short mhl16[32 * 136];  // 8.7 KB bf16: mh[e][k]
  __shared__ unsigned short tailsA[32 * 40];  // 2.5 KB A-frag: [edge][k], k>=20 zero pad
  __shared__ float    dif[32 * 4];            // dx,dy,dz,rad
  __shared__ int      sl[32], dl[32];
  __shared__ float    p_lds[4][16];

  const int t = threadIdx.x;
  const int lane = t & 63;
  const int w = t >> 6;
  const int mtile = w >> 1;                   // 0/1 (16-edge half)
  const int nhalf = w & 1;                    // 0/1 (64-col half)
  const int col = lane & 15;
  const int quad = lane >> 4;

  // stage W2 transposed as bf16 (proven v0 path)
  for (int i = t; i < 128 * 128; i += 256) {
    int k = i >> 7, n = i & 127;
    W2Ts[n * 136 + k] = f2b(W2[i]);
  }
  // zero tailsA once (stage rewrites words 0..9 per row; pad words 10..19 stay 0)
  for (int i = t; i < 32 * 20; i += 256) ((unsigned*)tailsA)[i] = 0u;

  // ---- persistent register state ----
  // tail B-frags: W1 rows 256..275 (20 tail features), K=32 zero-padded
  uint4v wtf[4];
  #pragma unroll
  for (int nt = 0; nt < 4; ++nt) {
    const int n = nhalf * 64 + nt * 16 + col;
    unsigned u[4];
    #pragma unroll
    for (int i = 0; i < 4; ++i) {
      const int k0 = quad * 8 + 2 * i;
      float a = (k0     < 20) ? W1[(size_t)(256 + k0    ) * 128 + n] : 0.f;
      float b = (k0 + 1 < 20) ? W1[(size_t)(256 + k0 + 1) * 128 + n] : 0.f;
      u[i] = pack2(a, b);
    }
    wtf[nt] = (uint4v){u[0], u[1], u[2], u[3]};
  }
  float b2reg[4], wvreg[4];
  #pragma unroll
  for (int nt = 0; nt < 4; ++nt) {
    const int n = (nhalf * 4 + nt) * 16 + col;
    b2reg[nt] = b2[n];
    wvreg[nt] = Wv[n];
  }
  const float bav = (MODE == 0) ? ba_p[0] : 0.f;
  __syncthreads();                            // tailsA zero/pad visible before first stage

  const int ntiles = (E + 31) >> 5;
  for (int tile = blockIdx.x; tile < ntiles; tile += gridDim.x) {
    const int e0 = tile * 32;
    // ---- phase 0: stage per-edge scalars + tail A-frag (bf16) ----
    if (t < 32) {
      int eg = e0 + t;
      int s = 0, d = 0;
      if (eg < E) { s = src[eg]; d = dst[eg]; }
      sl[t] = s; dl[t] = d;
      float dx = coords[s*3+0] - coords[d*3+0];
      float dy = coords[s*3+1] - coords[d*3+1];
      float dz = coords[s*3+2] - coords[d*3+2];
      float rad = sqrtf(dx*dx + dy*dy + dz*dz);
      dif[t*4+0] = dx; dif[t*4+1] = dy; dif[t*4+2] = dz; dif[t*4+3] = rad;
      unsigned* ta = (unsigned*)&tailsA[t * 40];
      ta[0] = pack2(rad, fabsf(dx));
      ta[1] = pack2(fabsf(dy), fabsf(dz));
    }
    #pragma unroll
    for (int i = t; i < 512; i += 256) {
      int e = i >> 4, f = i & 15;
      int eg = e0 + e;
      tailsA[e * 40 + 4 + f] =
          (eg < E) ? f2b(afeat[(size_t)eg * 16 + f]) : (unsigned short)0;
    }
    __syncthreads();                          // staged data visible

    // ---- issue A/B gathers for this wave's (edge r, feature nt) grid ----
    // lane (quad,col) owns edges e_r = mtile*16+quad*4+r, features n = nhalf*64+nt*16+col
    int er[4], sidx[4], didx[4];
    #pragma unroll
    for (int r = 0; r < 4; ++r) {
      er[r] = mtile * 16 + quad * 4 + r;
      sidx[r] = sl[er[r]]; didx[r] = dl[er[r]];
    }
    const int jbase = nhalf * 32 + (col >> 1);
    unsigned wa32[4][4], wb32[4][4];
    #pragma unroll
    for (int r = 0; r < 4; ++r) {
      const unsigned* ap = Apart + (size_t)sidx[r] * HP + jbase;
      const unsigned* bp = Bpart + (size_t)didx[r] * HP + jbase;
      #pragma unroll
      for (int nt = 0; nt < 4; ++nt) { wa32[r][nt] = ap[nt * 8]; wb32[r][nt] = bp[nt * 8]; }
    }

    // ---- tail MFMA: acct[nt][r] = tails(e_r) . W1tail[:, n] (C-layout == phase-A layout) ----
    float4v acct[4] = {{0,0,0,0},{0,0,0,0},{0,0,0,0},{0,0,0,0}};
    {
      const unsigned short* ap = &tailsA[(mtile * 16 + col) * 40 + quad * 8];
      short8 af = __builtin_bit_cast(short8, *(const uint4v*)ap);
      #pragma unroll
      for (int nt = 0; nt < 4; ++nt)
        acct[nt] = __builtin_amdgcn_mfma_f32_16x16x32_bf16(
            af, __builtin_bit_cast(short8, wtf[nt]), acct[nt], 0, 0, 0);
    }

    // ---- phase A: mh = silu(A[src] + B[dst] + tail) -> mhl16 (b16 scalar stores) ----
    const bool hiSel = (col & 1);
    #pragma unroll
    for (int r = 0; r < 4; ++r) {
      #pragma unroll
      for (int nt = 0; nt < 4; ++nt) {
        float va = hiSel ? bhi(wa32[r][nt]) : blo(wa32[r][nt]);
        float vb = hiSel ? bhi(wb32[r][nt]) : blo(wb32[r][nt]);
        float v = va + vb + acct[nt][r];
        mhl16[er[r] * 136 + nhalf * 64 + nt * 16 + col] = f2b(silu_f(v));
      }
    }
    __syncthreads();                          // mhl ready

    // ---- phase B: layer 2 via MFMA (A from mhl16, B from W2Ts) ----
    float4v acc[4] = {{0,0,0,0},{0,0,0,0},{0,0,0,0},{0,0,0,0}};
    {
      const unsigned short* abase = &mhl16[(mtile * 16 + col) * 136 + quad * 8];
      #pragma unroll
      for (int ks = 0; ks < 4; ++ks) {
        short8 af = __builtin_bit_cast(short8, *(const uint4v*)(abase + ks * 32));
        #pragma unroll
        for (int nt = 0; nt < 4; ++nt) {
          const unsigned short* bp =
              &W2Ts[((nhalf * 4 + nt) * 16 + col) * 136 + ks * 32 + quad * 8];
          short8 bf = __builtin_bit_cast(short8, *(const uint4v*)bp);
          acc[nt] = __builtin_amdgcn_mfma_f32_16x16x32_bf16(af, bf, acc[nt], 0, 0, 0);
        }
      }
    }

    // ---- epilogue: bias + silu + head dot, cross-wave reduce ----
    float p[4] = {0.f, 0.f, 0.f, 0.f};
    #pragma unroll
    for (int nt = 0; nt < 4; ++nt)
      #pragma unroll
      for (int r = 0; r < 4; ++r) {
        float v = silu_f(acc[nt][r] + b2reg[nt]);
        acc[nt][r] = v;                       // reuse acc as vv
        p[r] += v * wvreg[nt];
      }
    #pragma unroll
    for (int r = 0; r < 4; ++r) {
      #pragma unroll
      for (int off = 1; off < 16; off <<= 1) p[r] += __shfl_xor(p[r], off, 64);
    }
    if (col == 0) {
      #pragma unroll
      for (int r = 0; r < 4; ++r) p_lds[w][quad * 4 + r] = p[r];
    }
    __syncthreads();                          // p_lds ready

    // ---- scatter ----
    #pragma unroll
    for (int r = 0; r < 4; ++r) {
      const int le = quad * 4 + r;
      const int ei = mtile * 16 + le;
      const int eg = e0 + ei;
      const float pfull = p_lds[w][le] + p_lds[w ^ 1][le];
      if (MODE == 0) {
        if (eg < E) {
          float att = 1.f / (1.f + __expf(-(pfull + bav)));
          int d = dl[ei];
          #pragma unroll
          for (int nt = 0; nt < 4; ++nt) {
            int n = (nhalf * 4 + nt) * 16 + col;
            unsafeAtomicAdd(&out_agg[(size_t)d * HH + n], att * acc[nt][r]);
          }
        }
      } else {
        if (nhalf == 0 && eg < E && col < 3) {
          float rad = dif[ei * 4 + 3];
          float fac = pfull / (rad + 1.f);
          unsafeAtomicAdd(&out_agg[(size_t)dl[ei] * 3 + col], fac * dif[ei * 4 + col]);
        }
      }
    }
    __syncthreads();                          // protect LDS reuse next tile
  }
}

// ---------- 3) node MLP layer 1: g = silu([h, h_agg] @ Wn1 + bn1), bf16-packed ----------
__global__ __launch_bounds__(256) void node_l1_kernel(
    const float* __restrict__ h, const float* __restrict__ h_agg,
    const float* __restrict__ Wn1, const float* __restrict__ bn1,
    unsigned* __restrict__ g, int N)
{
  __shared__ unsigned Wl[256 * HP];           // 64 KB
  int t = threadIdx.x;
  const float2* W2 = (const float2*)Wn1;
  for (int i = t; i < 256 * HP; i += 256) { float2 w = W2[i]; Wl[i] = pack2(w.x, w.y); }
  __syncthreads();

  int wid = blockIdx.x * 4 + (t >> 6);
  int nw  = gridDim.x * 4;
  int jp  = t & 63;
  for (int n = wid; n < N; n += nw) {
    float a0 = bn1[2*jp], a1 = bn1[2*jp + 1];
    const float4* hn = (const float4*)(h + (size_t)n * HH);
    const float4* gn = (const float4*)(h_agg + (size_t)n * HH);
    #pragma unroll 4
    for (int k4 = 0; k4 < 32; ++k4) {
      float4 hv = hn[k4];
      float xs[4] = {hv.x, hv.y, hv.z, hv.w};
      #pragma unroll
      for (int u = 0; u < 4; ++u) {
        unsigned w = Wl[(4*k4 + u) * HP + jp];
        a0 += xs[u] * blo(w); a1 += xs[u] * bhi(w);
      }
    }
    #pragma unroll 4
    for (int k4 = 0; k4 < 32; ++k4) {
      float4 hv = gn[k4];
      float xs[4] = {hv.x, hv.y, hv.z, hv.w};
      #pragma unroll
      for (int u = 0; u < 4; ++u) {
        unsigned w = Wl[(128 + 4*k4 + u) * HP + jp];
        a0 += xs[u] * blo(w); a1 += xs[u] * bhi(w);
      }
    }
    g[(size_t)n * HP + jp] = pack2(silu_f(a0), silu_f(a1));
  }
}

// ---------- 4) node MLP layer 2: h_out = h + g @ Wn2 + bn2 ----------
__global__ __launch_bounds__(256) void node_l2_kernel(
    const unsigned* __restrict__ g, const float* __restrict__ h,
    const float* __restrict__ Wn2, const float* __restrict__ bn2,
    float* __restrict__ hout, int N)
{
  __shared__ unsigned Wl[128 * HP];           // 32 KB
  int t = threadIdx.x;
  const float2* W2 = (const float2*)Wn2;
  for (int i = t; i < 128 * HP; i += 256) { float2 w = W2[i]; Wl[i] = pack2(w.x, w.y); }
  __syncthreads();

  int wid = blockIdx.x * 4 + (t >> 6);
  int nw  = gridDim.x * 4;
  int jp  = t & 63;
  for (int n = wid; n < N; n += nw) {
    float a0 = bn2[2*jp], a1 = bn2[2*jp + 1];
    const uint2* gn = (const uint2*)(g + (size_t)n * HP);
    #pragma unroll 4
    for (int k2 = 0; k2 < 32; ++k2) {
      uint2 gp = gn[k2];                      // 4 bf16 inputs
      float x0 = blo(gp.x), x1 = bhi(gp.x), x2 = blo(gp.y), x3 = bhi(gp.y);
      unsigned w0 = Wl[(4*k2    ) * HP + jp];
      unsigned w1 = Wl[(4*k2 + 1) * HP + jp];
      unsigned w2 = Wl[(4*k2 + 2) * HP + jp];
      unsigned w3 = Wl[(4*k2 + 3) * HP + jp];
      a0 += x0*blo(w0) + x1*blo(w1) + x2*blo(w2) + x3*blo(w3);
      a1 += x0*bhi(w0) + x1*bhi(w1) + x2*bhi(w2) + x3*bhi(w3);
    }
    float2 hv = ((const float2*)h)[(size_t)n * HP + jp];
    ((float2*)hout)[(size_t)n * HP + jp] = make_float2(hv.x + a0, hv.y + a1);
  }
}

// ---------- 5) coords_out = coords + x_agg ----------
__global__ void coords_out_kernel(const float* __restrict__ coords,
                                  const float* __restrict__ x_agg,
                                  float* __restrict__ out, int n3)
{
  int i = blockIdx.x * blockDim.x + threadIdx.x;
  if (i < n3) out[i] = coords[i] + x_agg[i];
}

extern "C" void kernel_launch(void* const* d_in, const int* in_sizes, int n_in,
                              void* d_out, int out_size, void* d_ws, size_t ws_size,
                              hipStream_t stream)
{
  const float* h      = (const float*)d_in[0];
  const float* coords = (const float*)d_in[1];
  const float* afeat  = (const float*)d_in[2];
  const int*   src    = (const int*)d_in[3];
  const int*   dst    = (const int*)d_in[4];
  const float* We1 = (const float*)d_in[5];
  const float* be1 = (const float*)d_in[6];
  const float* We2 = (const float*)d_in[7];
  const float* be2 = (const float*)d_in[8];
  const float* Wa  = (const float*)d_in[9];
  const float* ba  = (const float*)d_in[10];
  const float* Wn1 = (const float*)d_in[11];
  const float* bn1 = (const float*)d_in[12];
  const float* Wn2 = (const float*)d_in[13];
  const float* bn2 = (const float*)d_in[14];
  const float* Wc1 = (const float*)d_in[15];
  const float* bc1 = (const float*)d_in[16];
  const float* Wc2 = (const float*)d_in[17];
  const float* bc2 = (const float*)d_in[18];
  const float* Wc3 = (const float*)d_in[19];

  const int E = in_sizes[3];
  const int N = in_sizes[0] / HH;

  unsigned* A1 = (unsigned*)d_ws;
  unsigned* B1 = A1 + (size_t)N * HP;
  unsigned* Ac = B1 + (size_t)N * HP;
  unsigned* Bc = Ac + (size_t)N * HP;
  float* h_agg = (float*)(Bc + (size_t)N * HP);
  float* x_agg = h_agg + (size_t)N * HH;
  unsigned* gbuf = A1;                        // reuse after edge kernels finish

  hipMemsetAsync(h_agg, 0, ((size_t)N * HH + (size_t)N * 3) * sizeof(float), stream);

  precompute_kernel<<<512, 256, 0, stream>>>(h, We1, be1, A1, B1, N);
  precompute_kernel<<<512, 256, 0, stream>>>(h, Wc1, bc1, Ac, Bc, N);

  edge_kernel<0><<<768, 256, 0, stream>>>(A1, B1, We1, We2, be2, Wa, ba,
                                          src, dst, coords, afeat, h_agg, E);
  edge_kernel<1><<<768, 256, 0, stream>>>(Ac, Bc, Wc1, Wc2, bc2, Wc3, nullptr,
                                          src, dst, coords, afeat, x_agg, E);

  node_l1_kernel<<<512, 256, 0, stream>>>(h, h_agg, Wn1, bn1, gbuf, N);
  node_l2_kernel<<<1024, 256, 0, stream>>>(gbuf, h, Wn2, bn2, (float*)d_out, N);
  coords_out_kernel<<<(N * 3 + 255) / 256, 256, 0, stream>>>(
      coords, x_agg, (float*)d_out + (size_t)N * HH, N * 3);
}

// Round 5
// 836.598 us; speedup vs baseline: 1.7775x; 1.3394x over previous
//
#include <hip/hip_runtime.h>
#include <math.h>

#define HH 128
#define HP 64   // u32 pairs per 128-feature row

typedef __attribute__((ext_vector_type(8))) short short8;
typedef __attribute__((ext_vector_type(4))) float float4v;
typedef __attribute__((ext_vector_type(4))) unsigned uint4v;

// ---------- helpers ----------
__device__ __forceinline__ float blo(unsigned w){ return __uint_as_float(w << 16); }
__device__ __forceinline__ float bhi(unsigned w){ return __uint_as_float(w & 0xffff0000u); }
__device__ __forceinline__ unsigned short f2b(float x){
  unsigned u = __float_as_uint(x);
  u += 0x7fffu + ((u >> 16) & 1u);           // RNE to bf16
  return (unsigned short)(u >> 16);
}
__device__ __forceinline__ unsigned pack2(float a, float b){
  return (unsigned)f2b(a) | ((unsigned)f2b(b) << 16);
}
__device__ __forceinline__ float silu_f(float x){ return x / (1.f + __expf(-x)); }

// ---------- 1) fused MFMA precompute: A1=h@We1[0:128]+be1, B1=h@We1[128:256],
//                                      Ac=h@Wc1[0:128]+bc1, Bc=h@Wc1[128:256] ----------
// 4 waves/block; wave w owns one output matrix, its 128x128 weight resident in regs.
// h-tile (16 nodes) staged once in LDS bf16, shared by all 4 waves. Double-buffered.
__global__ __launch_bounds__(256, 2) void precompute_mfma_kernel(
    const float* __restrict__ h,
    const float* __restrict__ We1, const float* __restrict__ be1,
    const float* __restrict__ Wc1, const float* __restrict__ bc1,
    unsigned* __restrict__ A1, unsigned* __restrict__ B1,
    unsigned* __restrict__ Ac, unsigned* __restrict__ Bc, int N)
{
  __shared__ unsigned short hs[2][16 * 136];  // 8.7 KB, stride 136: 2-way-free b128 reads

  const int t = threadIdx.x;
  const int lane = t & 63;
  const int w = t >> 6;
  const int col = lane & 15;
  const int quad = lane >> 4;

  const float* Wsel = (w < 2) ? We1 : Wc1;
  const int kb = (w & 1) * 128;               // row base within weight
  unsigned* outp = (w == 0) ? A1 : (w == 1) ? B1 : (w == 2) ? Ac : Bc;
  const float* biasp = (w == 0) ? be1 : (w == 2) ? bc1 : nullptr;

  // B-frags: lane holds W[k=ks*32+quad*8+2i..+2i+1][cn], bf16-paired (proven layout)
  uint4v wf[8][4];
  #pragma unroll
  for (int nt = 0; nt < 8; ++nt) {
    const int cn = nt * 16 + col;
    #pragma unroll
    for (int ks = 0; ks < 4; ++ks) {
      unsigned u[4];
      #pragma unroll
      for (int i = 0; i < 4; ++i) {
        const int k0 = kb + ks * 32 + quad * 8 + 2 * i;
        u[i] = pack2(Wsel[(size_t)k0 * 128 + cn], Wsel[(size_t)(k0 + 1) * 128 + cn]);
      }
      wf[nt][ks] = (uint4v){u[0], u[1], u[2], u[3]};
    }
  }
  float bias[8];
  #pragma unroll
  for (int nt = 0; nt < 8; ++nt) bias[nt] = biasp ? biasp[nt * 16 + col] : 0.f;

  const int ntiles = (N + 15) >> 4;
  auto stage = [&](int tl, int b) {
    const int n0s = tl * 16;
    for (int idx = t; idx < 16 * 64; idx += 256) {
      const int row = idx >> 6, jp = idx & 63;
      const int n = min(n0s + row, N - 1);
      float2 hv = ((const float2*)h)[(size_t)n * 64 + jp];
      ((unsigned*)&hs[b][row * 136])[jp] = pack2(hv.x, hv.y);
    }
  };

  int tile = blockIdx.x;
  if (tile < ntiles) stage(tile, 0);
  int buf = 0;
  for (; tile < ntiles; tile += gridDim.x, buf ^= 1) {
    __syncthreads();                          // hs[buf] ready; prev reads done
    if (tile + (int)gridDim.x < ntiles) stage(tile + gridDim.x, buf ^ 1);

    float4v acc[8] = {{0,0,0,0},{0,0,0,0},{0,0,0,0},{0,0,0,0},
                      {0,0,0,0},{0,0,0,0},{0,0,0,0},{0,0,0,0}};
    #pragma unroll
    for (int ks = 0; ks < 4; ++ks) {
      short8 af = __builtin_bit_cast(short8,
          *(const uint4v*)&hs[buf][col * 136 + ks * 32 + quad * 8]);
      #pragma unroll
      for (int nt = 0; nt < 8; ++nt)
        acc[nt] = __builtin_amdgcn_mfma_f32_16x16x32_bf16(
            af, __builtin_bit_cast(short8, wf[nt][ks]), acc[nt], 0, 0, 0);
    }
    const int n0 = tile * 16;
    #pragma unroll
    for (int nt = 0; nt < 8; ++nt) {
      #pragma unroll
      for (int r = 0; r < 4; ++r) {
        float v = acc[nt][r] + bias[nt];
        float o = __shfl_xor(v, 1, 64);       // neighbor col's value
        const int node = n0 + quad * 4 + r;
        if (!(lane & 1) && node < N)
          outp[(size_t)node * HP + ((nt * 16 + col) >> 1)] = pack2(v, o);
      }
    }
  }
}

// ---------- 2) MFMA edge kernels (v4, unchanged): MODE 0 = edge MLP, MODE 1 = coord MLP ----------
template<int MODE>
__global__ __launch_bounds__(256, 3) void edge_kernel(
    const unsigned* __restrict__ Apart, const unsigned* __restrict__ Bpart,
    const float* __restrict__ W1,       // (276,128); rows 256..275 = tail
    const float* __restrict__ W2, const float* __restrict__ b2,
    const float* __restrict__ Wv,       // Wa (mode0) or Wc3 (mode1), [128]
    const float* __restrict__ ba_p,     // ba (mode0), unused mode1
    const int* __restrict__ src, const int* __restrict__ dst,
    const float* __restrict__ coords, const float* __restrict__ afeat,
    float* __restrict__ out_agg, int E)
{
  __shared__ unsigned short W2Ts[128 * 136];  // 34 KB bf16, n-major: W2T[n][k]
  __shared__ unsigned short mhl16[32 * 136];  // 8.7 KB bf16: mh[e][k]
  __shared__ unsigned short tailsA[32 * 40];  // 2.5 KB A-frag: [edge][k], k>=20 zero pad
  __shared__ float    dif[32 * 4];            // dx,dy,dz,rad
  __shared__ int      sl[32], dl[32];
  __shared__ float    p_lds[4][16];

  const int t = threadIdx.x;
  const int lane = t & 63;
  const int w = t >> 6;
  const int mtile = w >> 1;                   // 0/1 (16-edge half)
  const int nhalf = w & 1;                    // 0/1 (64-col half)
  const int col = lane & 15;
  const int quad = lane >> 4;

  for (int i = t; i < 128 * 128; i += 256) {
    int k = i >> 7, n = i & 127;
    W2Ts[n * 136 + k] = f2b(W2[i]);
  }
  for (int i = t; i < 32 * 20; i += 256) ((unsigned*)tailsA)[i] = 0u;

  uint4v wtf[4];
  #pragma unroll
  for (int nt = 0; nt < 4; ++nt) {
    const int n = nhalf * 64 + nt * 16 + col;
    unsigned u[4];
    #pragma unroll
    for (int i = 0; i < 4; ++i) {
      const int k0 = quad * 8 + 2 * i;
      float a = (k0     < 20) ? W1[(size_t)(256 + k0    ) * 128 + n] : 0.f;
      float b = (k0 + 1 < 20) ? W1[(size_t)(256 + k0 + 1) * 128 + n] : 0.f;
      u[i] = pack2(a, b);
    }
    wtf[nt] = (uint4v){u[0], u[1], u[2], u[3]};
  }
  float b2reg[4], wvreg[4];
  #pragma unroll
  for (int nt = 0; nt < 4; ++nt) {
    const int n = (nhalf * 4 + nt) * 16 + col;
    b2reg[nt] = b2[n];
    wvreg[nt] = Wv[n];
  }
  const float bav = (MODE == 0) ? ba_p[0] : 0.f;
  __syncthreads();

  const int ntiles = (E + 31) >> 5;
  for (int tile = blockIdx.x; tile < ntiles; tile += gridDim.x) {
    const int e0 = tile * 32;
    if (t < 32) {
      int eg = e0 + t;
      int s = 0, d = 0;
      if (eg < E) { s = src[eg]; d = dst[eg]; }
      sl[t] = s; dl[t] = d;
      float dx = coords[s*3+0] - coords[d*3+0];
      float dy = coords[s*3+1] - coords[d*3+1];
      float dz = coords[s*3+2] - coords[d*3+2];
      float rad = sqrtf(dx*dx + dy*dy + dz*dz);
      dif[t*4+0] = dx; dif[t*4+1] = dy; dif[t*4+2] = dz; dif[t*4+3] = rad;
      unsigned* ta = (unsigned*)&tailsA[t * 40];
      ta[0] = pack2(rad, fabsf(dx));
      ta[1] = pack2(fabsf(dy), fabsf(dz));
    }
    #pragma unroll
    for (int i = t; i < 512; i += 256) {
      int e = i >> 4, f = i & 15;
      int eg = e0 + e;
      tailsA[e * 40 + 4 + f] =
          (eg < E) ? f2b(afeat[(size_t)eg * 16 + f]) : (unsigned short)0;
    }
    __syncthreads();

    int er[4], sidx[4], didx[4];
    #pragma unroll
    for (int r = 0; r < 4; ++r) {
      er[r] = mtile * 16 + quad * 4 + r;
      sidx[r] = sl[er[r]]; didx[r] = dl[er[r]];
    }
    const int jbase = nhalf * 32 + (col >> 1);
    unsigned wa32[4][4], wb32[4][4];
    #pragma unroll
    for (int r = 0; r < 4; ++r) {
      const unsigned* ap = Apart + (size_t)sidx[r] * HP + jbase;
      const unsigned* bp = Bpart + (size_t)didx[r] * HP + jbase;
      #pragma unroll
      for (int nt = 0; nt < 4; ++nt) { wa32[r][nt] = ap[nt * 8]; wb32[r][nt] = bp[nt * 8]; }
    }

    float4v acct[4] = {{0,0,0,0},{0,0,0,0},{0,0,0,0},{0,0,0,0}};
    {
      const unsigned short* ap = &tailsA[(mtile * 16 + col) * 40 + quad * 8];
      short8 af = __builtin_bit_cast(short8, *(const uint4v*)ap);
      #pragma unroll
      for (int nt = 0; nt < 4; ++nt)
        acct[nt] = __builtin_amdgcn_mfma_f32_16x16x32_bf16(
            af, __builtin_bit_cast(short8, wtf[nt]), acct[nt], 0, 0, 0);
    }

    const bool hiSel = (col & 1);
    #pragma unroll
    for (int r = 0; r < 4; ++r) {
      #pragma unroll
      for (int nt = 0; nt < 4; ++nt) {
        float va = hiSel ? bhi(wa32[r][nt]) : blo(wa32[r][nt]);
        float vb = hiSel ? bhi(wb32[r][nt]) : blo(wb32[r][nt]);
        float v = va + vb + acct[nt][r];
        mhl16[er[r] * 136 + nhalf * 64 + nt * 16 + col] = f2b(silu_f(v));
      }
    }
    __syncthreads();

    float4v acc[4] = {{0,0,0,0},{0,0,0,0},{0,0,0,0},{0,0,0,0}};
    {
      const unsigned short* abase = &mhl16[(mtile * 16 + col) * 136 + quad * 8];
      #pragma unroll
      for (int ks = 0; ks < 4; ++ks) {
        short8 af = __builtin_bit_cast(short8, *(const uint4v*)(abase + ks * 32));
        #pragma unroll
        for (int nt = 0; nt < 4; ++nt) {
          const unsigned short* bp =
              &W2Ts[((nhalf * 4 + nt) * 16 + col) * 136 + ks * 32 + quad * 8];
          short8 bf = __builtin_bit_cast(short8, *(const uint4v*)bp);
          acc[nt] = __builtin_amdgcn_mfma_f32_16x16x32_bf16(af, bf, acc[nt], 0, 0, 0);
        }
      }
    }

    float p[4] = {0.f, 0.f, 0.f, 0.f};
    #pragma unroll
    for (int nt = 0; nt < 4; ++nt)
      #pragma unroll
      for (int r = 0; r < 4; ++r) {
        float v = silu_f(acc[nt][r] + b2reg[nt]);
        acc[nt][r] = v;
        p[r] += v * wvreg[nt];
      }
    #pragma unroll
    for (int r = 0; r < 4; ++r) {
      #pragma unroll
      for (int off = 1; off < 16; off <<= 1) p[r] += __shfl_xor(p[r], off, 64);
    }
    if (col == 0) {
      #pragma unroll
      for (int r = 0; r < 4; ++r) p_lds[w][quad * 4 + r] = p[r];
    }
    __syncthreads();

    #pragma unroll
    for (int r = 0; r < 4; ++r) {
      const int le = quad * 4 + r;
      const int ei = mtile * 16 + le;
      const int eg = e0 + ei;
      const float pfull = p_lds[w][le] + p_lds[w ^ 1][le];
      if (MODE == 0) {
        if (eg < E) {
          float att = 1.f / (1.f + __expf(-(pfull + bav)));
          int d = dl[ei];
          #pragma unroll
          for (int nt = 0; nt < 4; ++nt) {
            int n = (nhalf * 4 + nt) * 16 + col;
            unsafeAtomicAdd(&out_agg[(size_t)d * HH + n], att * acc[nt][r]);
          }
        }
      } else {
        if (nhalf == 0 && eg < E && col < 3) {
          float rad = dif[ei * 4 + 3];
          float fac = pfull / (rad + 1.f);
          unsafeAtomicAdd(&out_agg[(size_t)dl[ei] * 3 + col], fac * dif[ei * 4 + col]);
        }
      }
    }
    __syncthreads();
  }
}

// ---------- 3) node MLP layer 1 via MFMA: g = silu([h, h_agg] @ Wn1 + bn1), bf16-packed ----------
// 4 waves/block, wave w owns 32 output cols (K=256 fragments in 64 VGPRs);
// [h|h_agg] 16-node tile staged once in LDS bf16, double-buffered.
__global__ __launch_bounds__(256, 4) void node_l1_mfma(
    const float* __restrict__ h, const float* __restrict__ h_agg,
    const float* __restrict__ Wn1, const float* __restrict__ bn1,
    unsigned* __restrict__ g, int N)
{
  __shared__ unsigned short xs[2][16 * 264];  // 16.9 KB, stride 264: 2-way-free b128 reads

  const int t = threadIdx.x;
  const int lane = t & 63;
  const int w = t >> 6;
  const int col = lane & 15;
  const int quad = lane >> 4;
  const int wbase = w * 32;

  uint4v wf[2][8];
  #pragma unroll
  for (int nt = 0; nt < 2; ++nt) {
    const int cn = wbase + nt * 16 + col;
    #pragma unroll
    for (int ks = 0; ks < 8; ++ks) {
      unsigned u[4];
      #pragma unroll
      for (int i = 0; i < 4; ++i) {
        const int k0 = ks * 32 + quad * 8 + 2 * i;
        u[i] = pack2(Wn1[(size_t)k0 * 128 + cn], Wn1[(size_t)(k0 + 1) * 128 + cn]);
      }
      wf[nt][ks] = (uint4v){u[0], u[1], u[2], u[3]};
    }
  }
  float bias[2] = { bn1[wbase + col], bn1[wbase + 16 + col] };

  const int ntiles = (N + 15) >> 4;
  auto stage = [&](int tl, int b) {
    const int n0s = tl * 16;
    for (int idx = t; idx < 16 * 128; idx += 256) {
      const int row = idx >> 7, jp = idx & 127;
      const int n = min(n0s + row, N - 1);
      float2 v = (jp < 64) ? ((const float2*)h)[(size_t)n * 64 + jp]
                           : ((const float2*)h_agg)[(size_t)n * 64 + (jp - 64)];
      ((unsigned*)&xs[b][row * 264])[jp] = pack2(v.x, v.y);
    }
  };

  int tile = blockIdx.x;
  if (tile < ntiles) stage(tile, 0);
  int buf = 0;
  for (; tile < ntiles; tile += gridDim.x, buf ^= 1) {
    __syncthreads();
    if (tile + (int)gridDim.x < ntiles) stage(tile + gridDim.x, buf ^ 1);

    float4v acc[2] = {{0,0,0,0},{0,0,0,0}};
    #pragma unroll
    for (int ks = 0; ks < 8; ++ks) {
      short8 af = __builtin_bit_cast(short8,
          *(const uint4v*)&xs[buf][col * 264 + ks * 32 + quad * 8]);
      acc[0] = __builtin_amdgcn_mfma_f32_16x16x32_bf16(
          af, __builtin_bit_cast(short8, wf[0][ks]), acc[0], 0, 0, 0);
      acc[1] = __builtin_amdgcn_mfma_f32_16x16x32_bf16(
          af, __builtin_bit_cast(short8, wf[1][ks]), acc[1], 0, 0, 0);
    }
    const int n0 = tile * 16;
    #pragma unroll
    for (int nt = 0; nt < 2; ++nt) {
      #pragma unroll
      for (int r = 0; r < 4; ++r) {
        float v = silu_f(acc[nt][r] + bias[nt]);
        float o = __shfl_xor(v, 1, 64);
        const int node = n0 + quad * 4 + r;
        if (!(lane & 1) && node < N)
          g[(size_t)node * HP + ((wbase + nt * 16 + col) >> 1)] = pack2(v, o);
      }
    }
  }
}

// ---------- 4) node MLP layer 2 via MFMA: h_out = h + g @ Wn2 + bn2 ----------
// Pure streaming: A-frags direct from global (bf16-packed g), weights in regs, no LDS/barriers.
__global__ __launch_bounds__(256, 4) void node_l2_mfma(
    const unsigned* __restrict__ g, const float* __restrict__ h,
    const float* __restrict__ Wn2, const float* __restrict__ bn2,
    float* __restrict__ hout, int N)
{
  const int t = threadIdx.x;
  const int lane = t & 63;
  const int w = t >> 6;
  const int col = lane & 15;
  const int quad = lane >> 4;
  const int wbase = w * 32;

  uint4v wf[2][4];
  #pragma unroll
  for (int nt = 0; nt < 2; ++nt) {
    const int cn = wbase + nt * 16 + col;
    #pragma unroll
    for (int ks = 0; ks < 4; ++ks) {
      unsigned u[4];
      #pragma unroll
      for (int i = 0; i < 4; ++i) {
        const int k0 = ks * 32 + quad * 8 + 2 * i;
        u[i] = pack2(Wn2[(size_t)k0 * 128 + cn], Wn2[(size_t)(k0 + 1) * 128 + cn]);
      }
      wf[nt][ks] = (uint4v){u[0], u[1], u[2], u[3]};
    }
  }
  float bias[2] = { bn2[wbase + col], bn2[wbase + 16 + col] };

  const int ntiles = (N + 15) >> 4;
  for (int tile = blockIdx.x; tile < ntiles; tile += gridDim.x) {
    const int n0 = tile * 16;
    const int na = min(n0 + col, N - 1);      // A-frag row (node) for this lane

    float4v acc[2] = {{0,0,0,0},{0,0,0,0}};
    #pragma unroll
    for (int ks = 0; ks < 4; ++ks) {
      short8 af = __builtin_bit_cast(short8,
          *(const uint4v*)(g + (size_t)na * HP + ks * 16 + quad * 4));
      acc[0] = __builtin_amdgcn_mfma_f32_16x16x32_bf16(
          af, __builtin_bit_cast(short8, wf[0][ks]), acc[0], 0, 0, 0);
      acc[1] = __builtin_amdgcn_mfma_f32_16x16x32_bf16(
          af, __builtin_bit_cast(short8, wf[1][ks]), acc[1], 0, 0, 0);
    }
    #pragma unroll
    for (int nt = 0; nt < 2; ++nt) {
      const int cn = wbase + nt * 16 + col;
      #pragma unroll
      for (int r = 0; r < 4; ++r) {
        const int node = n0 + quad * 4 + r;
        if (node < N) {
          float v = acc[nt][r] + bias[nt] + h[(size_t)node * HH + cn];
          hout[(size_t)node * HH + cn] = v;
        }
      }
    }
  }
}

// ---------- 5) coords_out = coords + x_agg ----------
__global__ void coords_out_kernel(const float* __restrict__ coords,
                                  const float* __restrict__ x_agg,
                                  float* __restrict__ out, int n3)
{
  int i = blockIdx.x * blockDim.x + threadIdx.x;
  if (i < n3) out[i] = coords[i] + x_agg[i];
}

extern "C" void kernel_launch(void* const* d_in, const int* in_sizes, int n_in,
                              void* d_out, int out_size, void* d_ws, size_t ws_size,
                              hipStream_t stream)
{
  const float* h      = (const float*)d_in[0];
  const float* coords = (const float*)d_in[1];
  const float* afeat  = (const float*)d_in[2];
  const int*   src    = (const int*)d_in[3];
  const int*   dst    = (const int*)d_in[4];
  const float* We1 = (const float*)d_in[5];
  const float* be1 = (const float*)d_in[6];
  const float* We2 = (const float*)d_in[7];
  const float* be2 = (const float*)d_in[8];
  const float* Wa  = (const float*)d_in[9];
  const float* ba  = (const float*)d_in[10];
  const float* Wn1 = (const float*)d_in[11];
  const float* bn1 = (const float*)d_in[12];
  const float* Wn2 = (const float*)d_in[13];
  const float* bn2 = (const float*)d_in[14];
  const float* Wc1 = (const float*)d_in[15];
  const float* bc1 = (const float*)d_in[16];
  const float* Wc2 = (const float*)d_in[17];
  const float* bc2 = (const float*)d_in[18];
  const float* Wc3 = (const float*)d_in[19];

  const int E = in_sizes[3];
  const int N = in_sizes[0] / HH;

  unsigned* A1 = (unsigned*)d_ws;
  unsigned* B1 = A1 + (size_t)N * HP;
  unsigned* Ac = B1 + (size_t)N * HP;
  unsigned* Bc = Ac + (size_t)N * HP;
  float* h_agg = (float*)(Bc + (size_t)N * HP);
  float* x_agg = h_agg + (size_t)N * HH;
  unsigned* gbuf = A1;                        // reuse after edge kernels finish

  hipMemsetAsync(h_agg, 0, ((size_t)N * HH + (size_t)N * 3) * sizeof(float), stream);

  precompute_mfma_kernel<<<512, 256, 0, stream>>>(h, We1, be1, Wc1, bc1,
                                                  A1, B1, Ac, Bc, N);

  edge_kernel<0><<<768, 256, 0, stream>>>(A1, B1, We1, We2, be2, Wa, ba,
                                          src, dst, coords, afeat, h_agg, E);
  edge_kernel<1><<<768, 256, 0, stream>>>(Ac, Bc, Wc1, Wc2, bc2, Wc3, nullptr,
                                          src, dst, coords, afeat, x_agg, E);

  node_l1_mfma<<<512, 256, 0, stream>>>(h, h_agg, Wn1, bn1, gbuf, N);
  node_l2_mfma<<<1024, 256, 0, stream>>>(gbuf, h, Wn2, bn2, (float*)d_out, N);
  coords_out_kernel<<<(N * 3 + 255) / 256, 256, 0, stream>>>(
      coords, x_agg, (float*)d_out + (size_t)N * HH, N * 3);
}

// Round 6
// 785.756 us; speedup vs baseline: 1.8925x; 1.0647x over previous
//
#include <hip/hip_runtime.h>
#include <math.h>

#define HH 128
#define HP 64   // u32 pairs per 128-feature row

typedef __attribute__((ext_vector_type(8))) short short8;
typedef __attribute__((ext_vector_type(4))) float float4v;
typedef __attribute__((ext_vector_type(4))) unsigned uint4v;

// ---------- helpers ----------
__device__ __forceinline__ float blo(unsigned w){ return __uint_as_float(w << 16); }
__device__ __forceinline__ float bhi(unsigned w){ return __uint_as_float(w & 0xffff0000u); }
__device__ __forceinline__ unsigned short f2b(float x){
  unsigned u = __float_as_uint(x);
  u += 0x7fffu + ((u >> 16) & 1u);           // RNE to bf16
  return (unsigned short)(u >> 16);
}
__device__ __forceinline__ unsigned pack2(float a, float b){
  return (unsigned)f2b(a) | ((unsigned)f2b(b) << 16);
}
__device__ __forceinline__ float silu_f(float x){ return x / (1.f + __expf(-x)); }

// ---------- 1) fused MFMA precompute ----------
// Output layout of A/B rows is PERMUTED for the edge kernel's dwordx4 gathers:
// pair index jp' = (n>>6)*32 + ((n&15)>>1)*4 + ((n>>4)&3)   [n = feature 0..127]
// so the 4 nt-values a lane needs are 16B-contiguous.
__global__ __launch_bounds__(256, 2) void precompute_mfma_kernel(
    const float* __restrict__ h,
    const float* __restrict__ We1, const float* __restrict__ be1,
    const float* __restrict__ Wc1, const float* __restrict__ bc1,
    unsigned* __restrict__ A1, unsigned* __restrict__ B1,
    unsigned* __restrict__ Ac, unsigned* __restrict__ Bc, int N)
{
  __shared__ unsigned short hs[2][16 * 136];  // 8.7 KB, stride 136

  const int t = threadIdx.x;
  const int lane = t & 63;
  const int w = t >> 6;
  const int col = lane & 15;
  const int quad = lane >> 4;

  const float* Wsel = (w < 2) ? We1 : Wc1;
  const int kb = (w & 1) * 128;               // row base within weight
  unsigned* outp = (w == 0) ? A1 : (w == 1) ? B1 : (w == 2) ? Ac : Bc;
  const float* biasp = (w == 0) ? be1 : (w == 2) ? bc1 : nullptr;

  uint4v wf[8][4];
  #pragma unroll
  for (int nt = 0; nt < 8; ++nt) {
    const int cn = nt * 16 + col;
    #pragma unroll
    for (int ks = 0; ks < 4; ++ks) {
      unsigned u[4];
      #pragma unroll
      for (int i = 0; i < 4; ++i) {
        const int k0 = kb + ks * 32 + quad * 8 + 2 * i;
        u[i] = pack2(Wsel[(size_t)k0 * 128 + cn], Wsel[(size_t)(k0 + 1) * 128 + cn]);
      }
      wf[nt][ks] = (uint4v){u[0], u[1], u[2], u[3]};
    }
  }
  float bias[8];
  #pragma unroll
  for (int nt = 0; nt < 8; ++nt) bias[nt] = biasp ? biasp[nt * 16 + col] : 0.f;

  const int ntiles = (N + 15) >> 4;
  auto stage = [&](int tl, int b) {
    const int n0s = tl * 16;
    for (int idx = t; idx < 16 * 64; idx += 256) {
      const int row = idx >> 6, jp = idx & 63;
      const int n = min(n0s + row, N - 1);
      float2 hv = ((const float2*)h)[(size_t)n * 64 + jp];
      ((unsigned*)&hs[b][row * 136])[jp] = pack2(hv.x, hv.y);
    }
  };

  int tile = blockIdx.x;
  if (tile < ntiles) stage(tile, 0);
  int buf = 0;
  for (; tile < ntiles; tile += gridDim.x, buf ^= 1) {
    __syncthreads();
    if (tile + (int)gridDim.x < ntiles) stage(tile + gridDim.x, buf ^ 1);

    float4v acc[8] = {{0,0,0,0},{0,0,0,0},{0,0,0,0},{0,0,0,0},
                      {0,0,0,0},{0,0,0,0},{0,0,0,0},{0,0,0,0}};
    #pragma unroll
    for (int ks = 0; ks < 4; ++ks) {
      short8 af = __builtin_bit_cast(short8,
          *(const uint4v*)&hs[buf][col * 136 + ks * 32 + quad * 8]);
      #pragma unroll
      for (int nt = 0; nt < 8; ++nt)
        acc[nt] = __builtin_amdgcn_mfma_f32_16x16x32_bf16(
            af, __builtin_bit_cast(short8, wf[nt][ks]), acc[nt], 0, 0, 0);
    }
    const int n0 = tile * 16;
    #pragma unroll
    for (int nt = 0; nt < 8; ++nt) {
      #pragma unroll
      for (int r = 0; r < 4; ++r) {
        float v = acc[nt][r] + bias[nt];
        float o = __shfl_xor(v, 1, 64);       // neighbor col's value
        const int node = n0 + quad * 4 + r;
        if (!(lane & 1) && node < N)
          outp[(size_t)node * HP + (nt >> 2) * 32 + ((col >> 1) << 2) + (nt & 3)]
              = pack2(v, o);
      }
    }
  }
}

// ---------- 2) MFMA edge kernels: MODE 0 = edge MLP (att -> h_agg), MODE 1 = coord MLP (-> x_agg) ----------
// v5 = v4 memory envelope (768 blocks, 3/CU, W2Ts in LDS, unsorted, plain atomics)
//    + cross-tile pipelined dwordx4 gathers (issued tile t, consumed tile t+1; no
//      barrier between issue and consume), triple-buffered staging, 2 barriers/tile.
template<int MODE>
__global__ __launch_bounds__(256, 3) void edge_kernel(
    const unsigned* __restrict__ Apart, const unsigned* __restrict__ Bpart,
    const float* __restrict__ W1,       // (276,128); rows 256..275 = tail
    const float* __restrict__ W2, const float* __restrict__ b2,
    const float* __restrict__ Wv,       // Wa (mode0) or Wc3 (mode1), [128]
    const float* __restrict__ ba_p,     // ba (mode0), unused mode1
    const int* __restrict__ src, const int* __restrict__ dst,
    const float* __restrict__ coords, const float* __restrict__ afeat,
    float* __restrict__ out_agg, int E)
{
  __shared__ unsigned short W2Ts[128 * 136];  // 34 KB bf16, n-major
  __shared__ unsigned short mhl16[32 * 136];  // 8.7 KB bf16: mh[e][k]
  __shared__ unsigned short tailsA[3][32 * 40]; // 7.5 KB A-frags, k>=20 zero pad
  __shared__ float    dif[3][32 * 4];         // dx,dy,dz,rad
  __shared__ int      sl[3][32], dl[3][32];
  __shared__ float    p_lds[4][16];

  const int t = threadIdx.x;
  const int lane = t & 63;
  const int w = t >> 6;
  const int mtile = w >> 1;                   // 0/1 (16-edge half)
  const int nhalf = w & 1;                    // 0/1 (64-col half)
  const int col = lane & 15;
  const int quad = lane >> 4;

  for (int i = t; i < 128 * 128; i += 256) {
    int k = i >> 7, n = i & 127;
    W2Ts[n * 136 + k] = f2b(W2[i]);
  }
  for (int i = t; i < 3 * 32 * 20; i += 256) ((unsigned*)tailsA)[i] = 0u;

  uint4v wtf[4];
  #pragma unroll
  for (int nt = 0; nt < 4; ++nt) {
    const int n = nhalf * 64 + nt * 16 + col;
    unsigned u[4];
    #pragma unroll
    for (int i = 0; i < 4; ++i) {
      const int k0 = quad * 8 + 2 * i;
      float a = (k0     < 20) ? W1[(size_t)(256 + k0    ) * 128 + n] : 0.f;
      float b = (k0 + 1 < 20) ? W1[(size_t)(256 + k0 + 1) * 128 + n] : 0.f;
      u[i] = pack2(a, b);
    }
    wtf[nt] = (uint4v){u[0], u[1], u[2], u[3]};
  }
  float b2reg[4], wvreg[4];
  #pragma unroll
  for (int nt = 0; nt < 4; ++nt) {
    const int n = (nhalf * 4 + nt) * 16 + col;
    b2reg[nt] = b2[n];
    wvreg[nt] = Wv[n];
  }
  const float bav = (MODE == 0) ? ba_p[0] : 0.f;

  // ---- stage per-edge scalars + tail A-frag into buffer b ----
  auto stage = [&](int tl, int b) {
    const int e0s = tl * 32;
    if (t < 32) {
      int eg = e0s + t;
      int s = 0, d = 0;
      if (eg < E) { s = src[eg]; d = dst[eg]; }
      sl[b][t] = s; dl[b][t] = d;
      float dx = coords[s*3+0] - coords[d*3+0];
      float dy = coords[s*3+1] - coords[d*3+1];
      float dz = coords[s*3+2] - coords[d*3+2];
      float rad = sqrtf(dx*dx + dy*dy + dz*dz);
      dif[b][t*4+0] = dx; dif[b][t*4+1] = dy;
      dif[b][t*4+2] = dz; dif[b][t*4+3] = rad;
      unsigned* ta = (unsigned*)&tailsA[b][t * 40];
      ta[0] = pack2(rad, fabsf(dx));
      ta[1] = pack2(fabsf(dy), fabsf(dz));
    }
    if (t < 128) {                            // afeat: 32 edges x 4 float4
      int e = t >> 2, q4 = t & 3;
      int eg = e0s + e;
      float4 v = make_float4(0.f, 0.f, 0.f, 0.f);
      if (eg < E) v = ((const float4*)afeat)[(size_t)eg * 4 + q4];
      unsigned* d4 = (unsigned*)&tailsA[b][e * 40 + 4 + q4 * 4];
      d4[0] = pack2(v.x, v.y);
      d4[1] = pack2(v.z, v.w);
    }
  };

  const int gs = gridDim.x;
  const int ntiles = (E + 31) >> 5;
  const int T0 = blockIdx.x;
  if (T0 < ntiles)      stage(T0, 0);
  if (T0 + gs < ntiles) stage(T0 + gs, 1);
  __syncthreads();                            // W2Ts + pads + stage(0,1) visible

  // ---- pipelined gathers: dwordx4 per (edge r, A/B) thanks to permuted layout ----
  uint4v wa4[4], wb4[4];
  const int jb4 = nhalf * 32 + ((col >> 1) << 2);
  auto issueG = [&](int b) {
    #pragma unroll
    for (int r = 0; r < 4; ++r) {
      const int e = mtile * 16 + quad * 4 + r;
      wa4[r] = *(const uint4v*)(Apart + (size_t)sl[b][e] * HP + jb4);
      wb4[r] = *(const uint4v*)(Bpart + (size_t)dl[b][e] * HP + jb4);
    }
  };
  if (T0 < ntiles) issueG(0);

  int buf = 0;
  for (int tile = T0; tile < ntiles; tile += gs, buf = (buf == 2) ? 0 : buf + 1) {
    const int e0 = tile * 32;

    // ---- tail MFMA: acct[nt][r] = tails(e_r) . W1tail[:, n] ----
    float4v acct[4] = {{0,0,0,0},{0,0,0,0},{0,0,0,0},{0,0,0,0}};
    {
      const unsigned short* ap = &tailsA[buf][(mtile * 16 + col) * 40 + quad * 8];
      short8 af = __builtin_bit_cast(short8, *(const uint4v*)ap);
      #pragma unroll
      for (int nt = 0; nt < 4; ++nt)
        acct[nt] = __builtin_amdgcn_mfma_f32_16x16x32_bf16(
            af, __builtin_bit_cast(short8, wtf[nt]), acct[nt], 0, 0, 0);
    }

    // ---- phase A: mh = silu(A[src] + B[dst] + tail) -> mhl16 ----
    const bool hiSel = (col & 1);
    #pragma unroll
    for (int r = 0; r < 4; ++r) {
      const int er_ = mtile * 16 + quad * 4 + r;
      #pragma unroll
      for (int nt = 0; nt < 4; ++nt) {
        unsigned ua = wa4[r][nt], ub = wb4[r][nt];
        float va = hiSel ? bhi(ua) : blo(ua);
        float vb = hiSel ? bhi(ub) : blo(ub);
        float v = va + vb + acct[nt][r];
        mhl16[er_ * 136 + nhalf * 64 + nt * 16 + col] = f2b(silu_f(v));
      }
    }
    __syncthreads();                          // B1: mhl visible; scatter(t-1) done -> buf reuse safe

    // ---- stage tile t+2 (after B1 rendezvous: no reader of that buffer remains) ----
    if (tile + 2 * gs < ntiles) stage(tile + 2 * gs, (buf == 0) ? 2 : buf - 1);

    // ---- phase B: layer 2 via MFMA ----
    float4v acc[4] = {{0,0,0,0},{0,0,0,0},{0,0,0,0},{0,0,0,0}};
    {
      const unsigned short* abase = &mhl16[(mtile * 16 + col) * 136 + quad * 8];
      #pragma unroll
      for (int ks = 0; ks < 4; ++ks) {
        short8 af = __builtin_bit_cast(short8, *(const uint4v*)(abase + ks * 32));
        #pragma unroll
        for (int nt = 0; nt < 4; ++nt) {
          const unsigned short* bp =
              &W2Ts[((nhalf * 4 + nt) * 16 + col) * 136 + ks * 32 + quad * 8];
          short8 bf = __builtin_bit_cast(short8, *(const uint4v*)bp);
          acc[nt] = __builtin_amdgcn_mfma_f32_16x16x32_bf16(af, bf, acc[nt], 0, 0, 0);
        }
      }
    }

    // ---- epilogue: bias + silu + head dot, cross-wave reduce ----
    float p[4] = {0.f, 0.f, 0.f, 0.f};
    #pragma unroll
    for (int nt = 0; nt < 4; ++nt)
      #pragma unroll
      for (int r = 0; r < 4; ++r) {
        float v = silu_f(acc[nt][r] + b2reg[nt]);
        acc[nt][r] = v;
        p[r] += v * wvreg[nt];
      }
    #pragma unroll
    for (int r = 0; r < 4; ++r) {
      #pragma unroll
      for (int off = 1; off < 16; off <<= 1) p[r] += __shfl_xor(p[r], off, 64);
    }
    if (col == 0) {
      #pragma unroll
      for (int r = 0; r < 4; ++r) p_lds[w][quad * 4 + r] = p[r];
    }
    __syncthreads();                          // B2: p_lds visible; mhl safe for next phase A

    // ---- issue next tile's gathers BEFORE the atomics (vmcnt is in-order:
    //      phase A's wait then doesn't have to drain the atomic stream) ----
    if (tile + gs < ntiles) issueG((buf == 2) ? 0 : buf + 1);

    // ---- scatter ----
    #pragma unroll
    for (int r = 0; r < 4; ++r) {
      const int le = quad * 4 + r;
      const int ei = mtile * 16 + le;
      const int eg = e0 + ei;
      const float pfull = p_lds[w][le] + p_lds[w ^ 1][le];
      if (MODE == 0) {
        if (eg < E) {
          float att = 1.f / (1.f + __expf(-(pfull + bav)));
          int d = dl[buf][ei];
          #pragma unroll
          for (int nt = 0; nt < 4; ++nt) {
            int n = (nhalf * 4 + nt) * 16 + col;
            unsafeAtomicAdd(&out_agg[(size_t)d * HH + n], att * acc[nt][r]);
          }
        }
      } else {
        if (nhalf == 0 && eg < E && col < 3) {
          float rad = dif[buf][ei * 4 + 3];
          float fac = pfull / (rad + 1.f);
          unsafeAtomicAdd(&out_agg[(size_t)dl[buf][ei] * 3 + col],
                          fac * dif[buf][ei * 4 + col]);
        }
      }
    }
    // no trailing barrier: B1 of the next iteration is the rendezvous
  }
}

// ---------- 3) node MLP layer 1 via MFMA ----------
__global__ __launch_bounds__(256, 4) void node_l1_mfma(
    const float* __restrict__ h, const float* __restrict__ h_agg,
    const float* __restrict__ Wn1, const float* __restrict__ bn1,
    unsigned* __restrict__ g, int N)
{
  __shared__ unsigned short xs[2][16 * 264];

  const int t = threadIdx.x;
  const int lane = t & 63;
  const int w = t >> 6;
  const int col = lane & 15;
  const int quad = lane >> 4;
  const int wbase = w * 32;

  uint4v wf[2][8];
  #pragma unroll
  for (int nt = 0; nt < 2; ++nt) {
    const int cn = wbase + nt * 16 + col;
    #pragma unroll
    for (int ks = 0; ks < 8; ++ks) {
      unsigned u[4];
      #pragma unroll
      for (int i = 0; i < 4; ++i) {
        const int k0 = ks * 32 + quad * 8 + 2 * i;
        u[i] = pack2(Wn1[(size_t)k0 * 128 + cn], Wn1[(size_t)(k0 + 1) * 128 + cn]);
      }
      wf[nt][ks] = (uint4v){u[0], u[1], u[2], u[3]};
    }
  }
  float bias[2] = { bn1[wbase + col], bn1[wbase + 16 + col] };

  const int ntiles = (N + 15) >> 4;
  auto stage = [&](int tl, int b) {
    const int n0s = tl * 16;
    for (int idx = t; idx < 16 * 128; idx += 256) {
      const int row = idx >> 7, jp = idx & 127;
      const int n = min(n0s + row, N - 1);
      float2 v = (jp < 64) ? ((const float2*)h)[(size_t)n * 64 + jp]
                           : ((const float2*)h_agg)[(size_t)n * 64 + (jp - 64)];
      ((unsigned*)&xs[b][row * 264])[jp] = pack2(v.x, v.y);
    }
  };

  int tile = blockIdx.x;
  if (tile < ntiles) stage(tile, 0);
  int buf = 0;
  for (; tile < ntiles; tile += gridDim.x, buf ^= 1) {
    __syncthreads();
    if (tile + (int)gridDim.x < ntiles) stage(tile + gridDim.x, buf ^ 1);

    float4v acc[2] = {{0,0,0,0},{0,0,0,0}};
    #pragma unroll
    for (int ks = 0; ks < 8; ++ks) {
      short8 af = __builtin_bit_cast(short8,
          *(const uint4v*)&xs[buf][col * 264 + ks * 32 + quad * 8]);
      acc[0] = __builtin_amdgcn_mfma_f32_16x16x32_bf16(
          af, __builtin_bit_cast(short8, wf[0][ks]), acc[0], 0, 0, 0);
      acc[1] = __builtin_amdgcn_mfma_f32_16x16x32_bf16(
          af, __builtin_bit_cast(short8, wf[1][ks]), acc[1], 0, 0, 0);
    }
    const int n0 = tile * 16;
    #pragma unroll
    for (int nt = 0; nt < 2; ++nt) {
      #pragma unroll
      for (int r = 0; r < 4; ++r) {
        float v = silu_f(acc[nt][r] + bias[nt]);
        float o = __shfl_xor(v, 1, 64);
        const int node = n0 + quad * 4 + r;
        if (!(lane & 1) && node < N)
          g[(size_t)node * HP + ((wbase + nt * 16 + col) >> 1)] = pack2(v, o);
      }
    }
  }
}

// ---------- 4) node MLP layer 2 via MFMA ----------
__global__ __launch_bounds__(256, 4) void node_l2_mfma(
    const unsigned* __restrict__ g, const float* __restrict__ h,
    const float* __restrict__ Wn2, const float* __restrict__ bn2,
    float* __restrict__ hout, int N)
{
  const int t = threadIdx.x;
  const int lane = t & 63;
  const int w = t >> 6;
  const int col = lane & 15;
  const int quad = lane >> 4;
  const int wbase = w * 32;

  uint4v wf[2][4];
  #pragma unroll
  for (int nt = 0; nt < 2; ++nt) {
    const int cn = wbase + nt * 16 + col;
    #pragma unroll
    for (int ks = 0; ks < 4; ++ks) {
      unsigned u[4];
      #pragma unroll
      for (int i = 0; i < 4; ++i) {
        const int k0 = ks * 32 + quad * 8 + 2 * i;
        u[i] = pack2(Wn2[(size_t)k0 * 128 + cn], Wn2[(size_t)(k0 + 1) * 128 + cn]);
      }
      wf[nt][ks] = (uint4v){u[0], u[1], u[2], u[3]};
    }
  }
  float bias[2] = { bn2[wbase + col], bn2[wbase + 16 + col] };

  const int ntiles = (N + 15) >> 4;
  for (int tile = blockIdx.x; tile < ntiles; tile += gridDim.x) {
    const int n0 = tile * 16;
    const int na = min(n0 + col, N - 1);

    float4v acc[2] = {{0,0,0,0},{0,0,0,0}};
    #pragma unroll
    for (int ks = 0; ks < 4; ++ks) {
      short8 af = __builtin_bit_cast(short8,
          *(const uint4v*)(g + (size_t)na * HP + ks * 16 + quad * 4));
      acc[0] = __builtin_amdgcn_mfma_f32_16x16x32_bf16(
          af, __builtin_bit_cast(short8, wf[0][ks]), acc[0], 0, 0, 0);
      acc[1] = __builtin_amdgcn_mfma_f32_16x16x32_bf16(
          af, __builtin_bit_cast(short8, wf[1][ks]), acc[1], 0, 0, 0);
    }
    #pragma unroll
    for (int nt = 0; nt < 2; ++nt) {
      const int cn = wbase + nt * 16 + col;
      #pragma unroll
      for (int r = 0; r < 4; ++r) {
        const int node = n0 + quad * 4 + r;
        if (node < N) {
          float v = acc[nt][r] + bias[nt] + h[(size_t)node * HH + cn];
          hout[(size_t)node * HH + cn] = v;
        }
      }
    }
  }
}

// ---------- 5) coords_out = coords + x_agg ----------
__global__ void coords_out_kernel(const float* __restrict__ coords,
                                  const float* __restrict__ x_agg,
                                  float* __restrict__ out, int n3)
{
  int i = blockIdx.x * blockDim.x + threadIdx.x;
  if (i < n3) out[i] = coords[i] + x_agg[i];
}

extern "C" void kernel_launch(void* const* d_in, const int* in_sizes, int n_in,
                              void* d_out, int out_size, void* d_ws, size_t ws_size,
                              hipStream_t stream)
{
  const float* h      = (const float*)d_in[0];
  const float* coords = (const float*)d_in[1];
  const float* afeat  = (const float*)d_in[2];
  const int*   src    = (const int*)d_in[3];
  const int*   dst    = (const int*)d_in[4];
  const float* We1 = (const float*)d_in[5];
  const float* be1 = (const float*)d_in[6];
  const float* We2 = (const float*)d_in[7];
  const float* be2 = (const float*)d_in[8];
  const float* Wa  = (const float*)d_in[9];
  const float* ba  = (const float*)d_in[10];
  const float* Wn1 = (const float*)d_in[11];
  const float* bn1 = (const float*)d_in[12];
  const float* Wn2 = (const float*)d_in[13];
  const float* bn2 = (const float*)d_in[14];
  const float* Wc1 = (const float*)d_in[15];
  const float* bc1 = (const float*)d_in[16];
  const float* Wc2 = (const float*)d_in[17];
  const float* bc2 = (const float*)d_in[18];
  const float* Wc3 = (const float*)d_in[19];

  const int E = in_sizes[3];
  const int N = in_sizes[0] / HH;

  unsigned* A1 = (unsigned*)d_ws;
  unsigned* B1 = A1 + (size_t)N * HP;
  unsigned* Ac = B1 + (size_t)N * HP;
  unsigned* Bc = Ac + (size_t)N * HP;
  float* h_agg = (float*)(Bc + (size_t)N * HP);
  float* x_agg = h_agg + (size_t)N * HH;
  unsigned* gbuf = A1;                        // reuse after edge kernels finish

  hipMemsetAsync(h_agg, 0, ((size_t)N * HH + (size_t)N * 3) * sizeof(float), stream);

  precompute_mfma_kernel<<<512, 256, 0, stream>>>(h, We1, be1, Wc1, bc1,
                                                  A1, B1, Ac, Bc, N);

  edge_kernel<0><<<768, 256, 0, stream>>>(A1, B1, We1, We2, be2, Wa, ba,
                                          src, dst, coords, afeat, h_agg, E);
  edge_kernel<1><<<768, 256, 0, stream>>>(Ac, Bc, Wc1, Wc2, bc2, Wc3, nullptr,
                                          src, dst, coords, afeat, x_agg, E);

  node_l1_mfma<<<512, 256, 0, stream>>>(h, h_agg, Wn1, bn1, gbuf, N);
  node_l2_mfma<<<1024, 256, 0, stream>>>(gbuf, h, Wn2, bn2, (float*)d_out, N);
  coords_out_kernel<<<(N * 3 + 255) / 256, 256, 0, stream>>>(
      coords, x_agg, (float*)d_out + (size_t)N * HH, N * 3);
}